// Round 2
// baseline (694.595 us; speedup 1.0000x reference)
//
#include <hip/hip_runtime.h>

#define NV 40962
#define NP 10242
#define KNB 7
#define C1 64
#define C2 64
#define C3 128
#define INC 8
#define OC 64
#define B 8
#define FCK (C3*NP)        // 1310976
#define NCHUNK (FCK/128)   // 10242
#define FBLK 1024

typedef __attribute__((ext_vector_type(8))) __bf16 bf16x8;
typedef __attribute__((ext_vector_type(4))) float f32x4;
typedef unsigned short ushort_t;
typedef unsigned int uint_t;

static __device__ __forceinline__ ushort_t f2bf(float f) {
    uint_t u = __float_as_uint(f);
    u = (u + 0x7FFFu + ((u >> 16) & 1u)) >> 16;
    return (ushort_t)u;
}
static __device__ __forceinline__ uint_t pack2(float a, float b) {
    return (uint_t)f2bf(a) | ((uint_t)f2bf(b) << 16);
}

// ---------------- merged prep: conv1 (blocks 0..1280) + weight swizzle (blocks 1281..1424) ----
__global__ __launch_bounds__(256) void k_pre(const float* __restrict__ x,
        const float* __restrict__ W1, const float* __restrict__ b1,
        ushort_t* __restrict__ h1bf, const float* __restrict__ W2,
        const float* __restrict__ W3, ushort_t* __restrict__ wsw) {
    __shared__ float sW[C1*INC];
    __shared__ float sb[C1];
    int tid = threadIdx.x;
    if (blockIdx.x >= 1281) {
        // weight swizzle: W2 -> fragment order, W3 -> fragment order
        int idx = (blockIdx.x - 1281)*256 + tid;
        if (idx < 28672) {
            int j = idx & 7, lane = (idx >> 3) & 63, rest = idx >> 9; // rest = kstep*4+ntile
            int ntile = rest & 3, kstep = rest >> 2;
            int quad = lane >> 4, col = lane & 15;
            int k = kstep*32 + quad*8 + j;
            int o = ntile*16 + col;
            int c = k & 63, knb = k >> 6;
            wsw[idx] = f2bf(W2[(size_t)o*(C1*KNB) + c*KNB + knb]);
        } else if (idx < 28672 + 8192) {
            int s = idx - 28672;
            int j = s & 7, lane = (s >> 3) & 63, rest = s >> 9;      // rest = kstep*8+ntile
            int ntile = rest & 7, kstep = rest >> 3;
            int quad = lane >> 4, col = lane & 15;
            int c = kstep*32 + quad*8 + j;
            int o3 = ntile*16 + col;
            wsw[idx] = f2bf(W3[(size_t)o3*C2 + c]);
        }
        return;
    }
    // conv1: h1bf[n][b][c] = bf16(relu(W1 @ x + b1))
    for (int i = tid; i < C1*INC; i += 256) sW[i] = W1[i];
    if (tid < C1) sb[tid] = b1[tid];
    __syncthreads();
    long g = (long)blockIdx.x*256 + tid;
    if (g >= (long)NV*B) return;
    int n = (int)(g >> 3);
    int b = (int)(g & 7);
    float xv[INC];
#pragma unroll
    for (int c = 0; c < INC; ++c) xv[c] = x[(size_t)b*INC*NV + (size_t)c*NV + n];
    uint4* outp = (uint4*)(h1bf + ((size_t)n*B + b)*C1);
#pragma unroll
    for (int og = 0; og < 8; ++og) {
        float h[8];
#pragma unroll
        for (int j = 0; j < 8; ++j) {
            int o = og*8 + j;
            float a = sb[o];
#pragma unroll
            for (int c = 0; c < INC; ++c) a += xv[c]*sW[o*INC + c];
            h[j] = fmaxf(a, 0.f);
        }
        uint4 u;
        u.x = pack2(h[0], h[1]); u.y = pack2(h[2], h[3]);
        u.z = pack2(h[4], h[5]); u.w = pack2(h[6], h[7]);
        outp[og] = u;
    }
}

// ---------------- conv2 MFMA: m = v*8+b (M=NV*8), K=448, N=64, 4 m-tiles/wave ----------
__global__ __launch_bounds__(256) void k_conv2m(const ushort_t* __restrict__ h1bf,
        const int* __restrict__ nebs, const ushort_t* __restrict__ wsw,
        const float* __restrict__ b2, ushort_t* __restrict__ h2bf) {
    int tid = threadIdx.x;
    int wave = tid >> 6, lane = tid & 63;
    int quad = lane >> 4, col = lane & 15;
    int bsub = col & 7;
    int mblock = blockIdx.x * 256;          // 256 m per block (4 waves x 4 tiles x 16)
    int mbase[4];
    int rowt[4][KNB];
    f32x4 acc[4][4];
#pragma unroll
    for (int t = 0; t < 4; ++t) {
        mbase[t] = mblock + wave*64 + t*16;
        int v = (mbase[t] + col) >> 3;
        int vc = v < NV ? v : 0;
#pragma unroll
        for (int kn = 0; kn < KNB; ++kn) rowt[t][kn] = nebs[(size_t)vc*KNB + kn];
#pragma unroll
        for (int nt = 0; nt < 4; ++nt) acc[t][nt] = (f32x4){0.f, 0.f, 0.f, 0.f};
    }
    float bv[4];
#pragma unroll
    for (int nt = 0; nt < 4; ++nt) bv[nt] = b2[nt*16 + col];
    const bf16x8* W = (const bf16x8*)wsw;
#pragma unroll
    for (int ks = 0; ks < 14; ++ks) {
        int knb = ks >> 1;
        int c0 = (ks & 1)*32 + quad*8;
        bf16x8 a[4];
#pragma unroll
        for (int t = 0; t < 4; ++t)
            a[t] = *(const bf16x8*)(h1bf + ((size_t)rowt[t][knb]*B + bsub)*C1 + c0);
#pragma unroll
        for (int nt = 0; nt < 4; ++nt) {
            bf16x8 bf = W[(ks*4 + nt)*64 + lane];
#pragma unroll
            for (int t = 0; t < 4; ++t)
                acc[t][nt] = __builtin_amdgcn_mfma_f32_16x16x32_bf16(a[t], bf, acc[t][nt], 0, 0, 0);
        }
    }
#pragma unroll
    for (int t = 0; t < 4; ++t) {
#pragma unroll
        for (int r = 0; r < 4; ++r) {
            int m = mbase[t] + quad*4 + r;
            if ((m >> 3) < NV) {
#pragma unroll
                for (int nt = 0; nt < 4; ++nt) {
                    float val = fmaxf(acc[t][nt][r] + bv[nt], 0.f);
                    h2bf[(size_t)m*C2 + nt*16 + col] = f2bf(val);
                }
            }
        }
    }
}

// ---------------- fused pool+conv3 MFMA: h3[b][o3][v], M=NP*8, N=128, K=64, 2 tiles/wave --
__global__ __launch_bounds__(256) void k_poolconv3(const ushort_t* __restrict__ h2bf,
        const int* __restrict__ nebs, const ushort_t* __restrict__ wsw3,
        const float* __restrict__ b3, float* __restrict__ h3) {
    int tid = threadIdx.x;
    int wave = tid >> 6, lane = tid & 63;
    int quad = lane >> 4, col = lane & 15;
    int m0 = blockIdx.x*128 + wave*32;      // 2 tiles of 16 per wave
    int rowt[2][KNB];
    int bsub[2];
#pragma unroll
    for (int t = 0; t < 2; ++t) {
        int m = m0 + t*16 + col;
        int mc = ((m >> 3) < NP) ? m : 0;
        int v = mc >> 3;
        bsub[t] = mc & 7;
#pragma unroll
        for (int kn = 0; kn < KNB; ++kn) rowt[t][kn] = nebs[(size_t)v*KNB + kn];
    }
    f32x4 acc[2][8];
#pragma unroll
    for (int t = 0; t < 2; ++t)
#pragma unroll
        for (int nt = 0; nt < 8; ++nt) acc[t][nt] = (f32x4){0.f, 0.f, 0.f, 0.f};
    float bv[8];
#pragma unroll
    for (int nt = 0; nt < 8; ++nt) bv[nt] = b3[nt*16 + col];
    const bf16x8* W = (const bf16x8*)wsw3;
#pragma unroll
    for (int ks = 0; ks < 2; ++ks) {
        bf16x8 a[2];
#pragma unroll
        for (int t = 0; t < 2; ++t) {
            float mx[8];
#pragma unroll
            for (int i = 0; i < 8; ++i) mx[i] = -1e30f;
#pragma unroll
            for (int kn = 0; kn < KNB; ++kn) {
                uint4 u = *(const uint4*)(h2bf + ((size_t)rowt[t][kn]*B + bsub[t])*C2 + ks*32 + quad*8);
                uint_t ws[4] = {u.x, u.y, u.z, u.w};
#pragma unroll
                for (int i = 0; i < 4; ++i) {
                    float lo = __uint_as_float((ws[i] & 0xFFFFu) << 16);
                    float hi = __uint_as_float(ws[i] & 0xFFFF0000u);
                    mx[2*i]   = fmaxf(mx[2*i], lo);
                    mx[2*i+1] = fmaxf(mx[2*i+1], hi);
                }
            }
            uint4 pk;   // exact: every mx equals one of the bf16 inputs, truncation is lossless
            pk.x = (__float_as_uint(mx[0]) >> 16) | (__float_as_uint(mx[1]) & 0xFFFF0000u);
            pk.y = (__float_as_uint(mx[2]) >> 16) | (__float_as_uint(mx[3]) & 0xFFFF0000u);
            pk.z = (__float_as_uint(mx[4]) >> 16) | (__float_as_uint(mx[5]) & 0xFFFF0000u);
            pk.w = (__float_as_uint(mx[6]) >> 16) | (__float_as_uint(mx[7]) & 0xFFFF0000u);
            __builtin_memcpy(&a[t], &pk, 16);
        }
#pragma unroll
        for (int nt = 0; nt < 8; ++nt) {
            bf16x8 bf = W[(ks*8 + nt)*64 + lane];
#pragma unroll
            for (int t = 0; t < 2; ++t)
                acc[t][nt] = __builtin_amdgcn_mfma_f32_16x16x32_bf16(a[t], bf, acc[t][nt], 0, 0, 0);
        }
    }
#pragma unroll
    for (int t = 0; t < 2; ++t) {
#pragma unroll
        for (int r = 0; r < 4; ++r) {
            int mm = m0 + t*16 + quad*4 + r;
            int vv = mm >> 3, b = mm & 7;
            if (vv < NP) {
#pragma unroll
                for (int nt = 0; nt < 8; ++nt) {
                    int o3 = nt*16 + col;
                    h3[(size_t)b*FCK + (size_t)o3*NP + vv] = fmaxf(acc[t][nt][r] + bv[nt], 0.f);
                }
            }
        }
    }
}

// ---------------- fc: split-K partials, XOR-swizzled float4 LDS (all ds_read_b128) --------
// swizzle: tile[row][slot ^ (row&7)] -- 8 distinct 16B slots per access = all 32 banks
__global__ __launch_bounds__(256) void k_fc(const float* __restrict__ h3,
        const float* __restrict__ Wfc, float* __restrict__ partial) {
    __shared__ f32x4 sW4[OC][32];   // sW4[o][i4 ^ (o&7)] = Wfc[o][i4*4..+3]
    __shared__ f32x4 sH4[B][32];    // sH4[b][i4 ^ b]     = h3[b][i4*4..+3]
    int tid = threadIdx.x;
    int wave = tid >> 6, lane = tid & 63;
    int o  = wave*16 + (lane & 15);     // each Wfc element read once per wave (4x broadcast)
    int bp = lane >> 4;
    int b0 = 2*bp, b1 = 2*bp + 1;
    float acc0 = 0.f, acc1 = 0.f;
    int sb_ = tid >> 5, si4 = tid & 31;
    for (int ch = blockIdx.x; ch < NCHUNK; ch += FBLK) {
        size_t i0 = (size_t)ch * 128;
        __syncthreads();
        // stage h3 chunk: 8 x 128 floats
        sH4[sb_][si4 ^ sb_] = *(const f32x4*)(h3 + (size_t)sb_*FCK + i0 + si4*4);
        // stage Wfc chunk: 64 x 128 floats
#pragma unroll
        for (int j = 0; j < 8; ++j) {
            int idx = j*256 + tid;
            int oo = idx >> 5, i4 = idx & 31;
            sW4[oo][i4 ^ (oo & 7)] = *(const f32x4*)(Wfc + (size_t)oo*FCK + i0 + i4*4);
        }
        __syncthreads();
#pragma unroll
        for (int i4 = 0; i4 < 32; ++i4) {
            f32x4 wv = sW4[o][i4 ^ (o & 7)];
            f32x4 h0 = sH4[b0][i4 ^ b0];
            f32x4 h1 = sH4[b1][i4 ^ b1];
            acc0 += wv.x*h0.x + wv.y*h0.y + wv.z*h0.z + wv.w*h0.w;
            acc1 += wv.x*h1.x + wv.y*h1.y + wv.z*h1.z + wv.w*h1.w;
        }
    }
    partial[((size_t)blockIdx.x*B + b0)*OC + o] = acc0;
    partial[((size_t)blockIdx.x*B + b1)*OC + o] = acc1;
}

// ---------------- fc reduce: 8 blocks x 256 threads, coalesced 256B reads ----------------
__global__ __launch_bounds__(256) void k_fcred(const float* __restrict__ partial,
        const float* __restrict__ bfc, float* __restrict__ out) {
    __shared__ float red[4][64];
    int b = blockIdx.x;
    int o = threadIdx.x & 63, jg = threadIdx.x >> 6;
    float s = 0.f;
    for (int j = jg; j < FBLK; j += 4) s += partial[((size_t)j*B + b)*OC + o];
    red[jg][o] = s;
    __syncthreads();
    if (jg == 0) out[b*OC + o] = red[0][o] + red[1][o] + red[2][o] + red[3][o] + bfc[o];
}

extern "C" void kernel_launch(void* const* d_in, const int* in_sizes, int n_in,
                              void* d_out, int out_size, void* d_ws, size_t ws_size,
                              hipStream_t stream) {
    const float* x    = (const float*)d_in[0];
    const int*   nebs = (const int*)d_in[1];
    const float* W1   = (const float*)d_in[2];
    const float* b1   = (const float*)d_in[3];
    const float* W2   = (const float*)d_in[4];
    const float* b2   = (const float*)d_in[5];
    const float* W3   = (const float*)d_in[6];
    const float* b3   = (const float*)d_in[7];
    const float* Wfc  = (const float*)d_in[8];
    const float* bfc  = (const float*)d_in[9];
    float* out = (float*)d_out;

    char* ws = (char*)d_ws;
    ushort_t* h1bf = (ushort_t*)(ws);                  // 41,945,088 B
    ushort_t* h2bf = (ushort_t*)(ws + 42000000);       // 41,945,088 B
    float*    h3   = (float*)(ws + 96000000);          // 41,951,232 B
    ushort_t* wsw  = (ushort_t*)(ws + 140000000);      // 73,728 B
    float*    part = (float*)(ws + 141000000);         // 2,097,152 B
    ushort_t* wsw3 = wsw + 28672;

    k_pre<<<1425, 256, 0, stream>>>(x, W1, b1, h1bf, W2, W3, wsw);
    k_conv2m<<<1281, 256, 0, stream>>>(h1bf, nebs, wsw, b2, h2bf);
    k_poolconv3<<<641, 256, 0, stream>>>(h2bf, nebs, wsw3, b3, h3);
    k_fc<<<FBLK, 256, 0, stream>>>(h3, Wfc, part);
    k_fcred<<<B, 256, 0, stream>>>(part, bfc, out);
}

// Round 3
// 670.330 us; speedup vs baseline: 1.0362x; 1.0362x over previous
//
#include <hip/hip_runtime.h>

#define NV 40962
#define NP 10242
#define KNB 7
#define C1 64
#define C2 64
#define C3 128
#define INC 8
#define OC 64
#define B 8
#define FCK (C3*NP)        // 1310976
#define NCHUNK (FCK/128)   // 10242
#define FBLK 1024

typedef __attribute__((ext_vector_type(8))) __bf16 bf16x8;
typedef __attribute__((ext_vector_type(4))) float f32x4;
typedef unsigned short ushort_t;
typedef unsigned int uint_t;

static __device__ __forceinline__ ushort_t f2bf(float f) {
    uint_t u = __float_as_uint(f);
    u = (u + 0x7FFFu + ((u >> 16) & 1u)) >> 16;
    return (ushort_t)u;
}
static __device__ __forceinline__ uint_t pack2(float a, float b) {
    return (uint_t)f2bf(a) | ((uint_t)f2bf(b) << 16);
}

// ---------------- weight swizzle: W2 -> Wsw (fragment order), W3 -> W3sw ----------------
__global__ __launch_bounds__(256) void k_wswz(const float* __restrict__ W2,
        const float* __restrict__ W3, ushort_t* __restrict__ wsw) {
    int idx = blockIdx.x*256 + threadIdx.x;
    if (idx < 28672) {
        int j = idx & 7, lane = (idx >> 3) & 63, rest = idx >> 9; // rest = kstep*4+ntile
        int ntile = rest & 3, kstep = rest >> 2;
        int quad = lane >> 4, col = lane & 15;
        int k = kstep*32 + quad*8 + j;
        int o = ntile*16 + col;
        int c = k & 63, knb = k >> 6;
        wsw[idx] = f2bf(W2[(size_t)o*(C1*KNB) + c*KNB + knb]);
    } else if (idx < 28672 + 8192) {
        int s = idx - 28672;
        int j = s & 7, lane = (s >> 3) & 63, rest = s >> 9;      // rest = kstep*8+ntile
        int ntile = rest & 7, kstep = rest >> 3;
        int quad = lane >> 4, col = lane & 15;
        int c = kstep*32 + quad*8 + j;
        int o3 = ntile*16 + col;
        wsw[idx] = f2bf(W3[(size_t)o3*C2 + c]);
    }
}

// ---------------- conv1: h1bf[n][b][c] = bf16(relu(W1 @ x + b1)) ----------------
__global__ __launch_bounds__(256) void k_conv1(const float* __restrict__ x,
        const float* __restrict__ W1, const float* __restrict__ b1,
        ushort_t* __restrict__ h1bf) {
    __shared__ float sW[C1*INC];
    __shared__ float sb[C1];
    int tid = threadIdx.x;
    for (int i = tid; i < C1*INC; i += 256) sW[i] = W1[i];
    if (tid < C1) sb[tid] = b1[tid];
    __syncthreads();
    long g = (long)blockIdx.x*256 + tid;
    if (g >= (long)NV*B) return;
    int n = (int)(g >> 3);
    int b = (int)(g & 7);
    float xv[INC];
#pragma unroll
    for (int c = 0; c < INC; ++c) xv[c] = x[(size_t)b*INC*NV + (size_t)c*NV + n];
    uint4* outp = (uint4*)(h1bf + ((size_t)n*B + b)*C1);
#pragma unroll
    for (int og = 0; og < 8; ++og) {
        float h[8];
#pragma unroll
        for (int j = 0; j < 8; ++j) {
            int o = og*8 + j;
            float a = sb[o];
#pragma unroll
            for (int c = 0; c < INC; ++c) a += xv[c]*sW[o*INC + c];
            h[j] = fmaxf(a, 0.f);
        }
        uint4 u;
        u.x = pack2(h[0], h[1]); u.y = pack2(h[2], h[3]);
        u.z = pack2(h[4], h[5]); u.w = pack2(h[6], h[7]);
        outp[og] = u;
    }
}

// ---------------- conv2 MFMA: m = v*8+b (M=NV*8), K=448, N=64 ----------------
__global__ __launch_bounds__(256) void k_conv2m(const ushort_t* __restrict__ h1bf,
        const int* __restrict__ nebs, const ushort_t* __restrict__ wsw,
        const float* __restrict__ b2, ushort_t* __restrict__ h2bf) {
    int tid = threadIdx.x;
    int wave = tid >> 6, lane = tid & 63;
    int quad = lane >> 4, col = lane & 15;
    int bsub = col & 7;
    int mblock = blockIdx.x * 128;
    int mbase[2];
    int rowt[2][KNB];
    f32x4 acc[2][4];
#pragma unroll
    for (int t = 0; t < 2; ++t) {
        mbase[t] = mblock + wave*32 + t*16;
        int v = (mbase[t] + col) >> 3;
        int vc = v < NV ? v : 0;
#pragma unroll
        for (int kn = 0; kn < KNB; ++kn) rowt[t][kn] = nebs[(size_t)vc*KNB + kn];
#pragma unroll
        for (int nt = 0; nt < 4; ++nt) acc[t][nt] = (f32x4){0.f, 0.f, 0.f, 0.f};
    }
    float bv[4];
#pragma unroll
    for (int nt = 0; nt < 4; ++nt) bv[nt] = b2[nt*16 + col];
    const bf16x8* W = (const bf16x8*)wsw;
#pragma unroll
    for (int ks = 0; ks < 14; ++ks) {
        int knb = ks >> 1;
        int c0 = (ks & 1)*32 + quad*8;
        bf16x8 a0 = *(const bf16x8*)(h1bf + ((size_t)rowt[0][knb]*B + bsub)*C1 + c0);
        bf16x8 a1 = *(const bf16x8*)(h1bf + ((size_t)rowt[1][knb]*B + bsub)*C1 + c0);
#pragma unroll
        for (int nt = 0; nt < 4; ++nt) {
            bf16x8 bf = W[(ks*4 + nt)*64 + lane];
            acc[0][nt] = __builtin_amdgcn_mfma_f32_16x16x32_bf16(a0, bf, acc[0][nt], 0, 0, 0);
            acc[1][nt] = __builtin_amdgcn_mfma_f32_16x16x32_bf16(a1, bf, acc[1][nt], 0, 0, 0);
        }
    }
#pragma unroll
    for (int t = 0; t < 2; ++t) {
#pragma unroll
        for (int r = 0; r < 4; ++r) {
            int m = mbase[t] + quad*4 + r;
            if ((m >> 3) < NV) {
#pragma unroll
                for (int nt = 0; nt < 4; ++nt) {
                    float val = fmaxf(acc[t][nt][r] + bv[nt], 0.f);
                    h2bf[(size_t)m*C2 + nt*16 + col] = f2bf(val);
                }
            }
        }
    }
}

// ---------------- pool: pbf[v][b][c] = max_k h2bf[neb][b][c] (bf16) ----------------
__global__ __launch_bounds__(256) void k_pool(const ushort_t* __restrict__ h2bf,
        const int* __restrict__ nebs, ushort_t* __restrict__ pbf) {
    long t = (long)blockIdx.x*256 + threadIdx.x;
    if (t >= (long)NP*32) return;
    int cg = (int)(t & 3);
    int b  = (int)((t >> 2) & 7);
    int v  = (int)(t >> 5);
    float m[16];
#pragma unroll
    for (int i = 0; i < 16; ++i) m[i] = -1e30f;
    for (int kn = 0; kn < KNB; ++kn) {
        int row = nebs[(size_t)v*KNB + kn];
        const uint4* src = (const uint4*)(h2bf + ((size_t)row*B + b)*C2 + cg*16);
        uint4 u0 = src[0], u1 = src[1];
        uint_t ws[8] = {u0.x, u0.y, u0.z, u0.w, u1.x, u1.y, u1.z, u1.w};
#pragma unroll
        for (int i = 0; i < 8; ++i) {
            float lo = __uint_as_float((ws[i] & 0xFFFFu) << 16);
            float hi = __uint_as_float(ws[i] & 0xFFFF0000u);
            m[2*i]   = fmaxf(m[2*i], lo);
            m[2*i+1] = fmaxf(m[2*i+1], hi);
        }
    }
    uint_t op[8];
#pragma unroll
    for (int i = 0; i < 8; ++i) {
        uint_t lo = __float_as_uint(m[2*i]) >> 16;            // exact (values are bf16)
        uint_t hi = __float_as_uint(m[2*i+1]) & 0xFFFF0000u;  // exact
        op[i] = lo | hi;
    }
    uint4* dst = (uint4*)(pbf + ((size_t)v*B + b)*C2 + cg*16);
    dst[0] = make_uint4(op[0], op[1], op[2], op[3]);
    dst[1] = make_uint4(op[4], op[5], op[6], op[7]);
}

// ---------------- conv3 MFMA: h3[b][o3][v], M=NP*8, N=128, K=64 ----------------
__global__ __launch_bounds__(256) void k_conv3m(const ushort_t* __restrict__ pbf,
        const ushort_t* __restrict__ wsw3, const float* __restrict__ b3,
        float* __restrict__ h3) {
    int tid = threadIdx.x;
    int wave = tid >> 6, lane = tid & 63;
    int quad = lane >> 4, col = lane & 15;
    int m0 = blockIdx.x*64 + wave*16;
    int m = m0 + col;
    int mc = ((m >> 3) < NP) ? m : 0;
    f32x4 acc[8];
#pragma unroll
    for (int nt = 0; nt < 8; ++nt) acc[nt] = (f32x4){0.f, 0.f, 0.f, 0.f};
    float bv[8];
#pragma unroll
    for (int nt = 0; nt < 8; ++nt) bv[nt] = b3[nt*16 + col];
    const bf16x8* W = (const bf16x8*)wsw3;
#pragma unroll
    for (int ks = 0; ks < 2; ++ks) {
        bf16x8 a = *(const bf16x8*)(pbf + (size_t)mc*C2 + ks*32 + quad*8);
#pragma unroll
        for (int nt = 0; nt < 8; ++nt) {
            bf16x8 bf = W[(ks*8 + nt)*64 + lane];
            acc[nt] = __builtin_amdgcn_mfma_f32_16x16x32_bf16(a, bf, acc[nt], 0, 0, 0);
        }
    }
#pragma unroll
    for (int r = 0; r < 4; ++r) {
        int mm = m0 + quad*4 + r;
        int v = mm >> 3, b = mm & 7;
        if (v < NP) {
#pragma unroll
            for (int nt = 0; nt < 8; ++nt) {
                int o3 = nt*16 + col;
                h3[(size_t)b*FCK + (size_t)o3*NP + v] = fmaxf(acc[nt][r] + bv[nt], 0.f);
            }
        }
    }
}

// ---------------- fc: split-K partials over chunks of 128 (float4 staging) ----------------
__global__ __launch_bounds__(256) void k_fc(const float* __restrict__ h3,
        const float* __restrict__ Wfc, float* __restrict__ partial) {
    __shared__ float sH[B][128];
    __shared__ float sW[OC][129];
    int tid = threadIdx.x;
    int o = tid & 63;
    int tb = tid >> 6;
    float acc0 = 0.f, acc1 = 0.f;
    for (int ch = blockIdx.x; ch < NCHUNK; ch += FBLK) {
        size_t i0 = (size_t)ch * 128;
        __syncthreads();
        {
            int bb = tid >> 5, i4 = tid & 31;
            float4 f = *(const float4*)(h3 + (size_t)bb*FCK + i0 + i4*4);
            sH[bb][i4*4+0] = f.x; sH[bb][i4*4+1] = f.y;
            sH[bb][i4*4+2] = f.z; sH[bb][i4*4+3] = f.w;
        }
#pragma unroll
        for (int j = 0; j < 8; ++j) {
            int idx = tid + j*256;
            int oo = idx >> 5, i4 = idx & 31;
            float4 f = *(const float4*)(Wfc + (size_t)oo*FCK + i0 + i4*4);
            sW[oo][i4*4+0] = f.x; sW[oo][i4*4+1] = f.y;
            sW[oo][i4*4+2] = f.z; sW[oo][i4*4+3] = f.w;
        }
        __syncthreads();
#pragma unroll 8
        for (int ii = 0; ii < 128; ++ii) {
            float w = sW[o][ii];
            acc0 += w * sH[2*tb][ii];
            acc1 += w * sH[2*tb+1][ii];
        }
    }
    partial[((size_t)blockIdx.x*B + 2*tb  )*OC + o] = acc0;
    partial[((size_t)blockIdx.x*B + 2*tb+1)*OC + o] = acc1;
}

// ---------------- fc reduce: 8 blocks x 256 threads, coalesced 256B wave reads ----------
__global__ __launch_bounds__(256) void k_fcred(const float* __restrict__ partial,
        const float* __restrict__ bfc, float* __restrict__ out) {
    __shared__ float red[4][64];
    int b = blockIdx.x;
    int o = threadIdx.x & 63, jg = threadIdx.x >> 6;
    float s = 0.f;
    for (int j = jg; j < FBLK; j += 4) s += partial[((size_t)j*B + b)*OC + o];
    red[jg][o] = s;
    __syncthreads();
    if (jg == 0) out[b*OC + o] = red[0][o] + red[1][o] + red[2][o] + red[3][o] + bfc[o];
}

extern "C" void kernel_launch(void* const* d_in, const int* in_sizes, int n_in,
                              void* d_out, int out_size, void* d_ws, size_t ws_size,
                              hipStream_t stream) {
    const float* x    = (const float*)d_in[0];
    const int*   nebs = (const int*)d_in[1];
    const float* W1   = (const float*)d_in[2];
    const float* b1   = (const float*)d_in[3];
    const float* W2   = (const float*)d_in[4];
    const float* b2   = (const float*)d_in[5];
    const float* W3   = (const float*)d_in[6];
    const float* b3   = (const float*)d_in[7];
    const float* Wfc  = (const float*)d_in[8];
    const float* bfc  = (const float*)d_in[9];
    float* out = (float*)d_out;

    char* ws = (char*)d_ws;
    ushort_t* h1bf = (ushort_t*)(ws);                  // 41,945,088 B
    ushort_t* h2bf = (ushort_t*)(ws + 42000000);       // 41,945,088 B
    ushort_t* pbf  = (ushort_t*)(ws + 84000000);       // 10,487,808 B
    float*    h3   = (float*)(ws + 96000000);          // 41,951,232 B
    ushort_t* wsw  = (ushort_t*)(ws + 140000000);      // 73,728 B
    float*    part = (float*)(ws + 141000000);         // 2,097,152 B
    ushort_t* wsw3 = wsw + 28672;

    k_wswz<<<144, 256, 0, stream>>>(W2, W3, wsw);
    k_conv1<<<1281, 256, 0, stream>>>(x, W1, b1, h1bf);
    k_conv2m<<<2561, 256, 0, stream>>>(h1bf, nebs, wsw, b2, h2bf);
    k_pool<<<1281, 256, 0, stream>>>(h2bf, nebs, pbf);
    k_conv3m<<<1281, 256, 0, stream>>>(pbf, wsw3, b3, h3);
    k_fc<<<FBLK, 256, 0, stream>>>(h3, Wfc, part);
    k_fcred<<<B, 256, 0, stream>>>(part, bfc, out);
}

// Round 4
// 669.117 us; speedup vs baseline: 1.0381x; 1.0018x over previous
//
#include <hip/hip_runtime.h>

#define NV 40962
#define NP 10242
#define KNB 7
#define C1 64
#define C2 64
#define C3 128
#define INC 8
#define OC 64
#define B 8
#define FCK (C3*NP)        // 1310976
#define NCHUNK (FCK/128)   // 10242
#define FBLK 1024

typedef __attribute__((ext_vector_type(8))) __bf16 bf16x8;
typedef __attribute__((ext_vector_type(4))) float f32x4;
typedef unsigned short ushort_t;
typedef unsigned int uint_t;

static __device__ __forceinline__ ushort_t f2bf(float f) {
    uint_t u = __float_as_uint(f);
    u = (u + 0x7FFFu + ((u >> 16) & 1u)) >> 16;
    return (ushort_t)u;
}
static __device__ __forceinline__ uint_t pack2(float a, float b) {
    return (uint_t)f2bf(a) | ((uint_t)f2bf(b) << 16);
}

// ---------------- weight swizzle: W2 -> Wsw (fragment order), W3 -> W3sw ----------------
__global__ __launch_bounds__(256) void k_wswz(const float* __restrict__ W2,
        const float* __restrict__ W3, ushort_t* __restrict__ wsw) {
    int idx = blockIdx.x*256 + threadIdx.x;
    if (idx < 28672) {
        int j = idx & 7, lane = (idx >> 3) & 63, rest = idx >> 9; // rest = kstep*4+ntile
        int ntile = rest & 3, kstep = rest >> 2;
        int quad = lane >> 4, col = lane & 15;
        int k = kstep*32 + quad*8 + j;
        int o = ntile*16 + col;
        int c = k & 63, knb = k >> 6;
        wsw[idx] = f2bf(W2[(size_t)o*(C1*KNB) + c*KNB + knb]);
    } else if (idx < 28672 + 8192) {
        int s = idx - 28672;
        int j = s & 7, lane = (s >> 3) & 63, rest = s >> 9;      // rest = kstep*8+ntile
        int ntile = rest & 7, kstep = rest >> 3;
        int quad = lane >> 4, col = lane & 15;
        int c = kstep*32 + quad*8 + j;
        int o3 = ntile*16 + col;
        wsw[idx] = f2bf(W3[(size_t)o3*C2 + c]);
    }
}

// ---------------- conv1: h1bf[n][b][c] = bf16(relu(W1 @ x + b1)) ----------------
__global__ __launch_bounds__(256) void k_conv1(const float* __restrict__ x,
        const float* __restrict__ W1, const float* __restrict__ b1,
        ushort_t* __restrict__ h1bf) {
    __shared__ float sW[C1*INC];
    __shared__ float sb[C1];
    int tid = threadIdx.x;
    for (int i = tid; i < C1*INC; i += 256) sW[i] = W1[i];
    if (tid < C1) sb[tid] = b1[tid];
    __syncthreads();
    long g = (long)blockIdx.x*256 + tid;
    if (g >= (long)NV*B) return;
    int n = (int)(g >> 3);
    int b = (int)(g & 7);
    float xv[INC];
#pragma unroll
    for (int c = 0; c < INC; ++c) xv[c] = x[(size_t)b*INC*NV + (size_t)c*NV + n];
    uint4* outp = (uint4*)(h1bf + ((size_t)n*B + b)*C1);
#pragma unroll
    for (int og = 0; og < 8; ++og) {
        float h[8];
#pragma unroll
        for (int j = 0; j < 8; ++j) {
            int o = og*8 + j;
            float a = sb[o];
#pragma unroll
            for (int c = 0; c < INC; ++c) a += xv[c]*sW[o*INC + c];
            h[j] = fmaxf(a, 0.f);
        }
        uint4 u;
        u.x = pack2(h[0], h[1]); u.y = pack2(h[2], h[3]);
        u.z = pack2(h[4], h[5]); u.w = pack2(h[6], h[7]);
        outp[og] = u;
    }
}

// ---------------- conv2 MFMA: m = v*8+b (M=NV*8), K=448, N=64 ----------------
__global__ __launch_bounds__(256) void k_conv2m(const ushort_t* __restrict__ h1bf,
        const int* __restrict__ nebs, const ushort_t* __restrict__ wsw,
        const float* __restrict__ b2, ushort_t* __restrict__ h2bf) {
    int tid = threadIdx.x;
    int wave = tid >> 6, lane = tid & 63;
    int quad = lane >> 4, col = lane & 15;
    int bsub = col & 7;
    int mblock = blockIdx.x * 128;
    int mbase[2];
    int rowt[2][KNB];
    f32x4 acc[2][4];
#pragma unroll
    for (int t = 0; t < 2; ++t) {
        mbase[t] = mblock + wave*32 + t*16;
        int v = (mbase[t] + col) >> 3;
        int vc = v < NV ? v : 0;
#pragma unroll
        for (int kn = 0; kn < KNB; ++kn) rowt[t][kn] = nebs[(size_t)vc*KNB + kn];
#pragma unroll
        for (int nt = 0; nt < 4; ++nt) acc[t][nt] = (f32x4){0.f, 0.f, 0.f, 0.f};
    }
    float bv[4];
#pragma unroll
    for (int nt = 0; nt < 4; ++nt) bv[nt] = b2[nt*16 + col];
    const bf16x8* W = (const bf16x8*)wsw;
#pragma unroll
    for (int ks = 0; ks < 14; ++ks) {
        int knb = ks >> 1;
        int c0 = (ks & 1)*32 + quad*8;
        bf16x8 a0 = *(const bf16x8*)(h1bf + ((size_t)rowt[0][knb]*B + bsub)*C1 + c0);
        bf16x8 a1 = *(const bf16x8*)(h1bf + ((size_t)rowt[1][knb]*B + bsub)*C1 + c0);
#pragma unroll
        for (int nt = 0; nt < 4; ++nt) {
            bf16x8 bf = W[(ks*4 + nt)*64 + lane];
            acc[0][nt] = __builtin_amdgcn_mfma_f32_16x16x32_bf16(a0, bf, acc[0][nt], 0, 0, 0);
            acc[1][nt] = __builtin_amdgcn_mfma_f32_16x16x32_bf16(a1, bf, acc[1][nt], 0, 0, 0);
        }
    }
#pragma unroll
    for (int t = 0; t < 2; ++t) {
#pragma unroll
        for (int r = 0; r < 4; ++r) {
            int m = mbase[t] + quad*4 + r;
            if ((m >> 3) < NV) {
#pragma unroll
                for (int nt = 0; nt < 4; ++nt) {
                    float val = fmaxf(acc[t][nt][r] + bv[nt], 0.f);
                    h2bf[(size_t)m*C2 + nt*16 + col] = f2bf(val);
                }
            }
        }
    }
}

// ---------------- pool: pbf[v][b][c] = max_k h2bf[neb][b][c] (bf16) ----------------
__global__ __launch_bounds__(256) void k_pool(const ushort_t* __restrict__ h2bf,
        const int* __restrict__ nebs, ushort_t* __restrict__ pbf) {
    long t = (long)blockIdx.x*256 + threadIdx.x;
    if (t >= (long)NP*32) return;
    int cg = (int)(t & 3);
    int b  = (int)((t >> 2) & 7);
    int v  = (int)(t >> 5);
    float m[16];
#pragma unroll
    for (int i = 0; i < 16; ++i) m[i] = -1e30f;
    for (int kn = 0; kn < KNB; ++kn) {
        int row = nebs[(size_t)v*KNB + kn];
        const uint4* src = (const uint4*)(h2bf + ((size_t)row*B + b)*C2 + cg*16);
        uint4 u0 = src[0], u1 = src[1];
        uint_t ws[8] = {u0.x, u0.y, u0.z, u0.w, u1.x, u1.y, u1.z, u1.w};
#pragma unroll
        for (int i = 0; i < 8; ++i) {
            float lo = __uint_as_float((ws[i] & 0xFFFFu) << 16);
            float hi = __uint_as_float(ws[i] & 0xFFFF0000u);
            m[2*i]   = fmaxf(m[2*i], lo);
            m[2*i+1] = fmaxf(m[2*i+1], hi);
        }
    }
    uint_t op[8];
#pragma unroll
    for (int i = 0; i < 8; ++i) {
        uint_t lo = __float_as_uint(m[2*i]) >> 16;            // exact (values are bf16)
        uint_t hi = __float_as_uint(m[2*i+1]) & 0xFFFF0000u;  // exact
        op[i] = lo | hi;
    }
    uint4* dst = (uint4*)(pbf + ((size_t)v*B + b)*C2 + cg*16);
    dst[0] = make_uint4(op[0], op[1], op[2], op[3]);
    dst[1] = make_uint4(op[4], op[5], op[6], op[7]);
}

// ---------------- conv3 MFMA: h3[b][o3][v], M=NP*8, N=128, K=64 ----------------
__global__ __launch_bounds__(256) void k_conv3m(const ushort_t* __restrict__ pbf,
        const ushort_t* __restrict__ wsw3, const float* __restrict__ b3,
        float* __restrict__ h3) {
    int tid = threadIdx.x;
    int wave = tid >> 6, lane = tid & 63;
    int quad = lane >> 4, col = lane & 15;
    int m0 = blockIdx.x*64 + wave*16;
    int m = m0 + col;
    int mc = ((m >> 3) < NP) ? m : 0;
    f32x4 acc[8];
#pragma unroll
    for (int nt = 0; nt < 8; ++nt) acc[nt] = (f32x4){0.f, 0.f, 0.f, 0.f};
    float bv[8];
#pragma unroll
    for (int nt = 0; nt < 8; ++nt) bv[nt] = b3[nt*16 + col];
    const bf16x8* W = (const bf16x8*)wsw3;
#pragma unroll
    for (int ks = 0; ks < 2; ++ks) {
        bf16x8 a = *(const bf16x8*)(pbf + (size_t)mc*C2 + ks*32 + quad*8);
#pragma unroll
        for (int nt = 0; nt < 8; ++nt) {
            bf16x8 bf = W[(ks*8 + nt)*64 + lane];
            acc[nt] = __builtin_amdgcn_mfma_f32_16x16x32_bf16(a, bf, acc[nt], 0, 0, 0);
        }
    }
#pragma unroll
    for (int r = 0; r < 4; ++r) {
        int mm = m0 + quad*4 + r;
        int v = mm >> 3, b = mm & 7;
        if (v < NP) {
#pragma unroll
            for (int nt = 0; nt < 8; ++nt) {
                int o3 = nt*16 + col;
                h3[(size_t)b*FCK + (size_t)o3*NP + v] = fmaxf(acc[nt][r] + bv[nt], 0.f);
            }
        }
    }
}

// ---------------- fc: register-blocked split-K; Wfc global->reg (no LDS), h3 via LDS ------
// 256 threads = 32 o-pairs x 8 k-slices(16). Wfc element read exactly once, straight to reg.
__global__ __launch_bounds__(256) void k_fc(const float* __restrict__ h3,
        const float* __restrict__ Wfc, float* __restrict__ partial) {
    __shared__ float sH[B][128];
    __shared__ float red[8][OC][8];   // [ks][o][b] = 16 KB
    int tid = threadIdx.x;
    int og = tid & 31;          // o-pair index: rows o0, o0+1
    int ks = tid >> 5;          // k-slice of 16 within the 128-chunk
    int o0 = og*2;
    float acc[2][8];
#pragma unroll
    for (int r = 0; r < 2; ++r)
#pragma unroll
        for (int b = 0; b < 8; ++b) acc[r][b] = 0.f;
    for (int ch = blockIdx.x; ch < NCHUNK; ch += FBLK) {
        size_t i0 = (size_t)ch * 128;
        __syncthreads();
        {   // stage h3 chunk (8 x 128 floats) with 256 f32x4 stores
            int bb = tid >> 5, i4 = tid & 31;
            *(f32x4*)&sH[bb][i4*4] = *(const f32x4*)(h3 + (size_t)bb*FCK + i0 + i4*4);
        }
        // Wfc direct to registers: 2 rows x 64 B contiguous per thread (full-sector reads)
        f32x4 w[2][4];
#pragma unroll
        for (int r = 0; r < 2; ++r)
#pragma unroll
            for (int q = 0; q < 4; ++q)
                w[r][q] = *(const f32x4*)(Wfc + (size_t)(o0+r)*FCK + i0 + ks*16 + q*4);
        __syncthreads();
#pragma unroll
        for (int b = 0; b < 8; ++b) {
#pragma unroll
            for (int q = 0; q < 4; ++q) {
                f32x4 h = *(const f32x4*)&sH[b][ks*16 + q*4];
#pragma unroll
                for (int r = 0; r < 2; ++r)
                    acc[r][b] += w[r][q].x*h.x + w[r][q].y*h.y + w[r][q].z*h.z + w[r][q].w*h.w;
            }
        }
    }
    // reduce partial sums across the 8 k-slices via LDS
#pragma unroll
    for (int r = 0; r < 2; ++r) {
        *(f32x4*)&red[ks][o0+r][0] = (f32x4){acc[r][0], acc[r][1], acc[r][2], acc[r][3]};
        *(f32x4*)&red[ks][o0+r][4] = (f32x4){acc[r][4], acc[r][5], acc[r][6], acc[r][7]};
    }
    __syncthreads();
#pragma unroll
    for (int i = 0; i < 2; ++i) {
        int idx = tid*2 + i;          // 0..511 -> (o,b)
        int o = idx >> 3, b = idx & 7;
        float s = 0.f;
#pragma unroll
        for (int k = 0; k < 8; ++k) s += red[k][o][b];
        partial[((size_t)blockIdx.x*B + b)*OC + o] = s;
    }
}

// ---------------- fc reduce: 8 blocks x 256 threads, coalesced 256B wave reads ----------
__global__ __launch_bounds__(256) void k_fcred(const float* __restrict__ partial,
        const float* __restrict__ bfc, float* __restrict__ out) {
    __shared__ float red[4][64];
    int b = blockIdx.x;
    int o = threadIdx.x & 63, jg = threadIdx.x >> 6;
    float s = 0.f;
    for (int j = jg; j < FBLK; j += 4) s += partial[((size_t)j*B + b)*OC + o];
    red[jg][o] = s;
    __syncthreads();
    if (jg == 0) out[b*OC + o] = red[0][o] + red[1][o] + red[2][o] + red[3][o] + bfc[o];
}

extern "C" void kernel_launch(void* const* d_in, const int* in_sizes, int n_in,
                              void* d_out, int out_size, void* d_ws, size_t ws_size,
                              hipStream_t stream) {
    const float* x    = (const float*)d_in[0];
    const int*   nebs = (const int*)d_in[1];
    const float* W1   = (const float*)d_in[2];
    const float* b1   = (const float*)d_in[3];
    const float* W2   = (const float*)d_in[4];
    const float* b2   = (const float*)d_in[5];
    const float* W3   = (const float*)d_in[6];
    const float* b3   = (const float*)d_in[7];
    const float* Wfc  = (const float*)d_in[8];
    const float* bfc  = (const float*)d_in[9];
    float* out = (float*)d_out;

    char* ws = (char*)d_ws;
    ushort_t* h1bf = (ushort_t*)(ws);                  // 41,945,088 B
    ushort_t* h2bf = (ushort_t*)(ws + 42000000);       // 41,945,088 B
    ushort_t* pbf  = (ushort_t*)(ws + 84000000);       // 10,487,808 B
    float*    h3   = (float*)(ws + 96000000);          // 41,951,232 B
    ushort_t* wsw  = (ushort_t*)(ws + 140000000);      // 73,728 B
    float*    part = (float*)(ws + 141000000);         // 2,097,152 B
    ushort_t* wsw3 = wsw + 28672;

    k_wswz<<<144, 256, 0, stream>>>(W2, W3, wsw);
    k_conv1<<<1281, 256, 0, stream>>>(x, W1, b1, h1bf);
    k_conv2m<<<2561, 256, 0, stream>>>(h1bf, nebs, wsw, b2, h2bf);
    k_pool<<<1281, 256, 0, stream>>>(h2bf, nebs, pbf);
    k_conv3m<<<1281, 256, 0, stream>>>(pbf, wsw3, b3, h3);
    k_fc<<<FBLK, 256, 0, stream>>>(h3, Wfc, part);
    k_fcred<<<B, 256, 0, stream>>>(part, bfc, out);
}

// Round 5
// 628.920 us; speedup vs baseline: 1.1044x; 1.0639x over previous
//
#include <hip/hip_runtime.h>

#define NV 40962
#define NP 10242
#define KNB 7
#define C1 64
#define C2 64
#define C3 128
#define INC 8
#define OC 64
#define B 8
#define FCK (C3*NP)        // 1310976
#define NBLK_FC 641        // ceil(NP*8 / 128)

typedef __attribute__((ext_vector_type(8))) __bf16 bf16x8;
typedef __attribute__((ext_vector_type(4))) float f32x4;
typedef unsigned short ushort_t;
typedef unsigned int uint_t;

static __device__ __forceinline__ ushort_t f2bf(float f) {
    uint_t u = __float_as_uint(f);
    u = (u + 0x7FFFu + ((u >> 16) & 1u)) >> 16;
    return (ushort_t)u;
}
static __device__ __forceinline__ uint_t pack2(float a, float b) {
    return (uint_t)f2bf(a) | ((uint_t)f2bf(b) << 16);
}

// ---------------- merged prep: conv1 (blocks 0..1280) + weight swizzle (1281..1424) ------
__global__ __launch_bounds__(256) void k_pre(const float* __restrict__ x,
        const float* __restrict__ W1, const float* __restrict__ b1,
        ushort_t* __restrict__ h1bf, const float* __restrict__ W2,
        const float* __restrict__ W3, ushort_t* __restrict__ wsw) {
    __shared__ float sW[C1*INC];
    __shared__ float sb[C1];
    int tid = threadIdx.x;
    if (blockIdx.x >= 1281) {
        int idx = (blockIdx.x - 1281)*256 + tid;
        if (idx < 28672) {
            int j = idx & 7, lane = (idx >> 3) & 63, rest = idx >> 9; // rest = kstep*4+ntile
            int ntile = rest & 3, kstep = rest >> 2;
            int quad = lane >> 4, col = lane & 15;
            int k = kstep*32 + quad*8 + j;
            int o = ntile*16 + col;
            int c = k & 63, knb = k >> 6;
            wsw[idx] = f2bf(W2[(size_t)o*(C1*KNB) + c*KNB + knb]);
        } else if (idx < 28672 + 8192) {
            int s = idx - 28672;
            int j = s & 7, lane = (s >> 3) & 63, rest = s >> 9;      // rest = kstep*8+ntile
            int ntile = rest & 7, kstep = rest >> 3;
            int quad = lane >> 4, col = lane & 15;
            int c = kstep*32 + quad*8 + j;
            int o3 = ntile*16 + col;
            wsw[idx] = f2bf(W3[(size_t)o3*C2 + c]);
        }
        return;
    }
    for (int i = tid; i < C1*INC; i += 256) sW[i] = W1[i];
    if (tid < C1) sb[tid] = b1[tid];
    __syncthreads();
    long g = (long)blockIdx.x*256 + tid;
    if (g >= (long)NV*B) return;
    int n = (int)(g >> 3);
    int b = (int)(g & 7);
    float xv[INC];
#pragma unroll
    for (int c = 0; c < INC; ++c) xv[c] = x[(size_t)b*INC*NV + (size_t)c*NV + n];
    uint4* outp = (uint4*)(h1bf + ((size_t)n*B + b)*C1);
#pragma unroll
    for (int og = 0; og < 8; ++og) {
        float h[8];
#pragma unroll
        for (int j = 0; j < 8; ++j) {
            int o = og*8 + j;
            float a = sb[o];
#pragma unroll
            for (int c = 0; c < INC; ++c) a += xv[c]*sW[o*INC + c];
            h[j] = fmaxf(a, 0.f);
        }
        uint4 u;
        u.x = pack2(h[0], h[1]); u.y = pack2(h[2], h[3]);
        u.z = pack2(h[4], h[5]); u.w = pack2(h[6], h[7]);
        outp[og] = u;
    }
}

// ---------------- conv2 MFMA: m = v*8+b (M=NV*8), K=448, N=64 ----------------
__global__ __launch_bounds__(256) void k_conv2m(const ushort_t* __restrict__ h1bf,
        const int* __restrict__ nebs, const ushort_t* __restrict__ wsw,
        const float* __restrict__ b2, ushort_t* __restrict__ h2bf) {
    int tid = threadIdx.x;
    int wave = tid >> 6, lane = tid & 63;
    int quad = lane >> 4, col = lane & 15;
    int bsub = col & 7;
    int mblock = blockIdx.x * 128;
    int mbase[2];
    int rowt[2][KNB];
    f32x4 acc[2][4];
#pragma unroll
    for (int t = 0; t < 2; ++t) {
        mbase[t] = mblock + wave*32 + t*16;
        int v = (mbase[t] + col) >> 3;
        int vc = v < NV ? v : 0;
#pragma unroll
        for (int kn = 0; kn < KNB; ++kn) rowt[t][kn] = nebs[(size_t)vc*KNB + kn];
#pragma unroll
        for (int nt = 0; nt < 4; ++nt) acc[t][nt] = (f32x4){0.f, 0.f, 0.f, 0.f};
    }
    float bv[4];
#pragma unroll
    for (int nt = 0; nt < 4; ++nt) bv[nt] = b2[nt*16 + col];
    const bf16x8* W = (const bf16x8*)wsw;
#pragma unroll
    for (int ks = 0; ks < 14; ++ks) {
        int knb = ks >> 1;
        int c0 = (ks & 1)*32 + quad*8;
        bf16x8 a0 = *(const bf16x8*)(h1bf + ((size_t)rowt[0][knb]*B + bsub)*C1 + c0);
        bf16x8 a1 = *(const bf16x8*)(h1bf + ((size_t)rowt[1][knb]*B + bsub)*C1 + c0);
#pragma unroll
        for (int nt = 0; nt < 4; ++nt) {
            bf16x8 bf = W[(ks*4 + nt)*64 + lane];
            acc[0][nt] = __builtin_amdgcn_mfma_f32_16x16x32_bf16(a0, bf, acc[0][nt], 0, 0, 0);
            acc[1][nt] = __builtin_amdgcn_mfma_f32_16x16x32_bf16(a1, bf, acc[1][nt], 0, 0, 0);
        }
    }
#pragma unroll
    for (int t = 0; t < 2; ++t) {
#pragma unroll
        for (int r = 0; r < 4; ++r) {
            int m = mbase[t] + quad*4 + r;
            if ((m >> 3) < NV) {
#pragma unroll
                for (int nt = 0; nt < 4; ++nt) {
                    float val = fmaxf(acc[t][nt][r] + bv[nt], 0.f);
                    h2bf[(size_t)m*C2 + nt*16 + col] = f2bf(val);
                }
            }
        }
    }
}

// ---------------- pool: pbf[v][b][c] = max_k h2bf[neb][b][c] (bf16) ----------------
__global__ __launch_bounds__(256) void k_pool(const ushort_t* __restrict__ h2bf,
        const int* __restrict__ nebs, ushort_t* __restrict__ pbf) {
    long t = (long)blockIdx.x*256 + threadIdx.x;
    if (t >= (long)NP*32) return;
    int cg = (int)(t & 3);
    int b  = (int)((t >> 2) & 7);
    int v  = (int)(t >> 5);
    float m[16];
#pragma unroll
    for (int i = 0; i < 16; ++i) m[i] = -1e30f;
    for (int kn = 0; kn < KNB; ++kn) {
        int row = nebs[(size_t)v*KNB + kn];
        const uint4* src = (const uint4*)(h2bf + ((size_t)row*B + b)*C2 + cg*16);
        uint4 u0 = src[0], u1 = src[1];
        uint_t ws[8] = {u0.x, u0.y, u0.z, u0.w, u1.x, u1.y, u1.z, u1.w};
#pragma unroll
        for (int i = 0; i < 8; ++i) {
            float lo = __uint_as_float((ws[i] & 0xFFFFu) << 16);
            float hi = __uint_as_float(ws[i] & 0xFFFF0000u);
            m[2*i]   = fmaxf(m[2*i], lo);
            m[2*i+1] = fmaxf(m[2*i+1], hi);
        }
    }
    uint_t op[8];
#pragma unroll
    for (int i = 0; i < 8; ++i) {
        uint_t lo = __float_as_uint(m[2*i]) >> 16;            // exact (values are bf16)
        uint_t hi = __float_as_uint(m[2*i+1]) & 0xFFFF0000u;  // exact
        op[i] = lo | hi;
    }
    uint4* dst = (uint4*)(pbf + ((size_t)v*B + b)*C2 + cg*16);
    dst[0] = make_uint4(op[0], op[1], op[2], op[3]);
    dst[1] = make_uint4(op[4], op[5], op[6], op[7]);
}

// ---------------- fused conv3 + fc: 641 blocks x 512 thr -------------------------------
// phase A: conv3 tile (16 v x 8 b x 128 o3) -> fp32 LDS (skewed). numerics = old h3 path.
// phase B: stream Wfc columns for this v-tile (each element once) against the LDS tile.
// element mloc of column o3 sits at sH3[o3*128 + ((mloc + ((o3&31)<<2)) & 127)]
__global__ __launch_bounds__(512) void k_pc3fc(const ushort_t* __restrict__ pbf,
        const ushort_t* __restrict__ wsw3, const float* __restrict__ b3,
        const float* __restrict__ Wfc, float* __restrict__ partial) {
    __shared__ float sH3[128*128];    // 64 KB
    __shared__ float red[8][OC][8];   // 16 KB
    int tid = threadIdx.x;
    // bijective chunked XCD swizzle (m204): v-adjacent blocks co-XCD for L2 sector dedup
    int bid = blockIdx.x;
    const int q = NBLK_FC/8, r = NBLK_FC%8;      // 80, 1
    int xcd = bid & 7, cidx = bid >> 3;
    int blk = (xcd < r) ? (xcd*(q+1) + cidx) : (r*(q+1) + (xcd-r)*q + cidx);
    int v0 = blk*16;
    // ---- phase A ----
    int wave = tid >> 6, lane = tid & 63;
    int quad = lane >> 4, col = lane & 15;
    int m0 = blk*128 + wave*16;
    int m = m0 + col;
    int mc = ((m >> 3) < NP) ? m : 0;
    f32x4 acc[8];
#pragma unroll
    for (int nt = 0; nt < 8; ++nt) acc[nt] = (f32x4){0.f, 0.f, 0.f, 0.f};
    float bv[8];
#pragma unroll
    for (int nt = 0; nt < 8; ++nt) bv[nt] = b3[nt*16 + col];
    const bf16x8* W = (const bf16x8*)wsw3;
#pragma unroll
    for (int ks = 0; ks < 2; ++ks) {
        bf16x8 a = *(const bf16x8*)(pbf + (size_t)mc*C2 + ks*32 + quad*8);
#pragma unroll
        for (int nt = 0; nt < 8; ++nt) {
            bf16x8 bf = W[(ks*8 + nt)*64 + lane];
            acc[nt] = __builtin_amdgcn_mfma_f32_16x16x32_bf16(a, bf, acc[nt], 0, 0, 0);
        }
    }
#pragma unroll
    for (int nt = 0; nt < 8; ++nt) {
        int o3 = nt*16 + col;
        int mlb = wave*16 + quad*4;
        f32x4 vals;
#pragma unroll
        for (int r4 = 0; r4 < 4; ++r4) {
            int mm = m0 + quad*4 + r4;
            vals[r4] = ((mm >> 3) < NP) ? fmaxf(acc[nt][r4] + bv[nt], 0.f) : 0.f;
        }
        int off = (mlb + ((o3 & 31) << 2)) & 127;   // stays 4-aligned, no 4-run wrap
        *(f32x4*)&sH3[o3*128 + off] = vals;
    }
    __syncthreads();
    // ---- phase B ----
    int o = tid & 63, ksl = tid >> 6;               // 64 o x 8 slices of 16 o3
    float fa[8];
#pragma unroll
    for (int b = 0; b < 8; ++b) fa[b] = 0.f;
    const float* wrow = Wfc + (size_t)o*FCK + v0;
    if (v0 + 16 <= NP) {
        for (int j = 0; j < 16; ++j) {
            int o3 = ksl*16 + j;
            float wv[16];
            __builtin_memcpy(wv, wrow + (size_t)o3*NP, 64);   // 8B-aligned safe
            const float* hrow = &sH3[o3*128];
            int skew = (o3 & 31) << 2;
#pragma unroll
            for (int vl = 0; vl < 16; ++vl) {
                int base = (vl*8 + skew) & 127;
                f32x4 h0 = *(const f32x4*)&hrow[base];
                f32x4 h1 = *(const f32x4*)&hrow[(base + 4) & 127];
                float w = wv[vl];
                fa[0] += w*h0.x; fa[1] += w*h0.y; fa[2] += w*h0.z; fa[3] += w*h0.w;
                fa[4] += w*h1.x; fa[5] += w*h1.y; fa[6] += w*h1.z; fa[7] += w*h1.w;
            }
        }
    } else {
        int nv = NP - v0;                            // tail block only
        for (int j = 0; j < 16; ++j) {
            int o3 = ksl*16 + j;
            const float* hrow = &sH3[o3*128];
            int skew = (o3 & 31) << 2;
            for (int vl = 0; vl < nv; ++vl) {
                int base = (vl*8 + skew) & 127;
                f32x4 h0 = *(const f32x4*)&hrow[base];
                f32x4 h1 = *(const f32x4*)&hrow[(base + 4) & 127];
                float w = wrow[(size_t)o3*NP + vl];
                fa[0] += w*h0.x; fa[1] += w*h0.y; fa[2] += w*h0.z; fa[3] += w*h0.w;
                fa[4] += w*h1.x; fa[5] += w*h1.y; fa[6] += w*h1.z; fa[7] += w*h1.w;
            }
        }
    }
    *(f32x4*)&red[ksl][o][0] = (f32x4){fa[0], fa[1], fa[2], fa[3]};
    *(f32x4*)&red[ksl][o][4] = (f32x4){fa[4], fa[5], fa[6], fa[7]};
    __syncthreads();
    float s = 0.f;
#pragma unroll
    for (int k = 0; k < 8; ++k) s += red[k][o][ksl];
    partial[((size_t)blk*B + ksl)*OC + o] = s;       // ksl doubles as batch index
}

// ---------------- fc reduce: 8 blocks x 256 threads, coalesced 256B wave reads ----------
__global__ __launch_bounds__(256) void k_fcred(const float* __restrict__ partial,
        const float* __restrict__ bfc, float* __restrict__ out) {
    __shared__ float red[4][64];
    int b = blockIdx.x;
    int o = threadIdx.x & 63, jg = threadIdx.x >> 6;
    float s = 0.f;
    for (int j = jg; j < NBLK_FC; j += 4) s += partial[((size_t)j*B + b)*OC + o];
    red[jg][o] = s;
    __syncthreads();
    if (jg == 0) out[b*OC + o] = red[0][o] + red[1][o] + red[2][o] + red[3][o] + bfc[o];
}

extern "C" void kernel_launch(void* const* d_in, const int* in_sizes, int n_in,
                              void* d_out, int out_size, void* d_ws, size_t ws_size,
                              hipStream_t stream) {
    const float* x    = (const float*)d_in[0];
    const int*   nebs = (const int*)d_in[1];
    const float* W1   = (const float*)d_in[2];
    const float* b1   = (const float*)d_in[3];
    const float* W2   = (const float*)d_in[4];
    const float* b2   = (const float*)d_in[5];
    const float* W3   = (const float*)d_in[6];
    const float* b3   = (const float*)d_in[7];
    const float* Wfc  = (const float*)d_in[8];
    const float* bfc  = (const float*)d_in[9];
    float* out = (float*)d_out;

    char* ws = (char*)d_ws;
    ushort_t* h1bf = (ushort_t*)(ws);                  // 41,945,088 B
    ushort_t* h2bf = (ushort_t*)(ws + 42000000);       // 41,945,088 B
    ushort_t* pbf  = (ushort_t*)(ws + 84000000);       // 10,487,808 B
    ushort_t* wsw  = (ushort_t*)(ws + 140000000);      // 73,728 B
    float*    part = (float*)(ws + 141000000);         // 1,312,768 B
    ushort_t* wsw3 = wsw + 28672;

    k_pre<<<1425, 256, 0, stream>>>(x, W1, b1, h1bf, W2, W3, wsw);
    k_conv2m<<<2561, 256, 0, stream>>>(h1bf, nebs, wsw, b2, h2bf);
    k_pool<<<1281, 256, 0, stream>>>(h2bf, nebs, pbf);
    k_pc3fc<<<NBLK_FC, 512, 0, stream>>>(pbf, wsw3, b3, Wfc, part);
    k_fcred<<<B, 256, 0, stream>>>(part, bfc, out);
}